// Round 11
// baseline (328.816 us; speedup 1.0000x reference)
//
#include <hip/hip_runtime.h>

#define T_TOK 8192
#define DIN   4096
#define DOUTF 4096
#define RANK  16

#define BM 256
#define BN 256
#define BK 128                 // i8 elements per K-tile = 128 B rows
#define NT (DIN / BK)          // 32 K-tiles
#define NPAIR (NT / 2)         // 16 iterations, 2 K-tiles each

typedef __attribute__((ext_vector_type(4))) float f32x4;
typedef __attribute__((ext_vector_type(4))) int   i32x4;
typedef __attribute__((ext_vector_type(8))) short bf16x8;

#define GLB_PTR(p) ((const __attribute__((address_space(1))) void*)(p))
#define LDS_PTR(p) ((__attribute__((address_space(3))) void*)(p))

__device__ __forceinline__ unsigned short f2bf(float f) {
  unsigned u = __float_as_uint(f);
  u = (u + 0x7fffu + ((u >> 16) & 1u)) >> 16;  // RNE
  return (unsigned short)u;
}

// ---------------------------------------------------------------- fused prep
// blocks [0,128): HEAVY -- lora_h via MFMA + x absmax + x quant.
//   16 tokens/wave (full 16x16x32 A-operand: row=lane&15=token, k=(lane>>4)*8+j).
//   wa staged ONCE per block into LDS as bf16 [16 r][512 k(+8 pad)] chunks ->
//   B-frag = one ds_read_b128 (wa aggregate 512MB -> 32MB). Mixed-adapter
//   blocks (rare) loop the distinct-adapter list with zero-masked A rows.
//   Pass2: re-read the block's 64 rows (L3-hot) coalesced, quantize to i8.
// blocks [128,1152): LIGHT -- per-row quant of base_w (unchanged, proven).
__global__ __launch_bounds__(256) void prep(const float* __restrict__ x,
                                            const float* __restrict__ base_w,
                                            const float* __restrict__ wa,
                                            const float* __restrict__ scaling,
                                            const int* __restrict__ segment,
                                            const int* __restrict__ lora_ids,
                                            signed char* __restrict__ xq,
                                            float* __restrict__ sx,
                                            signed char* __restrict__ wq,
                                            float* __restrict__ sw,
                                            float* __restrict__ hbuf,
                                            unsigned short* __restrict__ hb16,
                                            int* __restrict__ tokid) {
  const int tid = threadIdx.x;
  const int lane = tid & 63;
  const int wave = tid >> 6;

  if (blockIdx.x >= 128) {
    // ---------------- LIGHT: w-quant, one row per wave, reg-cached
    const int row = (blockIdx.x - 128) * 4 + wave;
    const float* rp = base_w + (size_t)row * DIN;
    f32x4 v[16];
    float amax = 0.f;
#pragma unroll
    for (int it = 0; it < 16; ++it) {
      v[it] = *(const f32x4*)(rp + it * 256 + lane * 4);
#pragma unroll
      for (int e = 0; e < 4; ++e) amax = fmaxf(amax, fabsf(v[it][e]));
    }
#pragma unroll
    for (int o = 1; o < 64; o <<= 1) amax = fmaxf(amax, __shfl_xor(amax, o));
    const float inv = amax > 0.f ? 127.0f / amax : 0.f;
    if (lane == 0) sw[row] = amax * (1.0f / 127.0f);
    signed char* op = wq + (size_t)row * DIN;
#pragma unroll
    for (int it = 0; it < 16; ++it) {
      const int q0 = (int)rintf(v[it][0] * inv);
      const int q1 = (int)rintf(v[it][1] * inv);
      const int q2 = (int)rintf(v[it][2] * inv);
      const int q3 = (int)rintf(v[it][3] * inv);
      *(int*)(op + it * 256 + lane * 4) =
          (q0 & 255) | ((q1 & 255) << 8) | ((q2 & 255) << 16) | ((q3 & 255) << 24);
    }
    return;
  }

  // ---------------- HEAVY: 64 tokens/block, 16 per wave
  __shared__ __align__(16) unsigned short wch[16][520];  // [r][k] bf16, +8 pad
  __shared__ float amax_l[64];
  __shared__ int ids_l[64];
  __shared__ int alist[8];
  __shared__ int s_na;

  const int T0 = blockIdx.x * 64;
  const int Tw = T0 + wave * 16;
  const int r15 = lane & 15;
  const int kg = lane >> 4;

  if (tid < 64) {
    const int t = T0 + tid;
    int s = 0;
#pragma unroll
    for (int i = 1; i < 8; ++i)
      if (t >= segment[i]) s = i;
    ids_l[tid] = lora_ids[s];
  }
  __syncthreads();
  if (tid == 0) {
    int na = 0;
    for (int i = 0; i < 64; ++i) {
      const int id = ids_l[i];
      bool dup = false;
      for (int q = 0; q < na; ++q) dup = dup || (alist[q] == id);
      if (!dup) alist[na++] = id;
    }
    s_na = na;
  }
  __syncthreads();

  const int myId = ids_l[wave * 16 + r15];  // adapter of my A-row token
  const int myTok = Tw + r15;
  const int na = s_na;

  f32x4 hacc = {0.f, 0.f, 0.f, 0.f};
  float amax = 0.f;

  for (int ai = 0; ai < na; ++ai) {
    const int a = alist[ai];
    const float* wabase = wa + (size_t)a * (DIN * RANK);
    const unsigned long long mm = __ballot(myId == a);
    const bool active = (mm != 0ull);
    for (int c = 0; c < 8; ++c) {
      __syncthreads();  // wch free (all readers of previous chunk done)
      // ---- stage chunk c: thread owns k = {2*tid, 2*tid+1}, all 16 ranks
      {
        const float* gp = wabase + (size_t)(c * 512 + 2 * tid) * RANK;
        f32x4 w[8];
#pragma unroll
        for (int i = 0; i < 8; ++i) w[i] = *(const f32x4*)(gp + i * 4);
#pragma unroll
        for (int r = 0; r < 16; ++r) {
          const unsigned lo = f2bf(w[r >> 2][r & 3]);
          const unsigned hi = f2bf(w[4 + (r >> 2)][r & 3]);
          *(unsigned*)&wch[r][2 * tid] = lo | (hi << 16);
        }
      }
      __syncthreads();
      if (ai == 0 || active) {
#pragma unroll 4
        for (int s = 0; s < 16; ++s) {
          const int kl = s * 32 + kg * 8;
          const float* xp = x + (size_t)myTok * DIN + c * 512 + kl;
          f32x4 x0 = *(const f32x4*)xp;
          f32x4 x1 = *(const f32x4*)(xp + 4);
          if (ai == 0) {
#pragma unroll
            for (int e = 0; e < 4; ++e)
              amax = fmaxf(amax, fmaxf(fabsf(x0[e]), fabsf(x1[e])));
          }
          bf16x8 af;
#pragma unroll
          for (int e = 0; e < 4; ++e) {
            af[e] = (short)f2bf(x0[e]);
            af[4 + e] = (short)f2bf(x1[e]);
          }
          if (myId != a) af = (bf16x8){0, 0, 0, 0, 0, 0, 0, 0};
          const bf16x8 bf = *(const bf16x8*)&wch[r15][kl];
          hacc = __builtin_amdgcn_mfma_f32_16x16x32_bf16(af, bf, hacc, 0, 0, 0);
        }
      }
    }
  }

  // absmax: combine the 4 k-group lanes of each token row
  amax = fmaxf(amax, __shfl_xor(amax, 16));
  amax = fmaxf(amax, __shfl_xor(amax, 32));
  if (lane < 16) amax_l[wave * 16 + lane] = amax;

  // h output: D col=lane&15=rank, row=(lane>>4)*4+reg=token (m89 layout)
#pragma unroll
  for (int e = 0; e < 4; ++e) {
    const int li = wave * 16 + kg * 4 + e;
    const int t = T0 + li;
    const float sc = scaling[ids_l[li]];
    const float hv = hacc[e] * sc;
    hbuf[t * RANK + r15] = hv;
    hb16[t * RANK + r15] = f2bf(hv);
  }

  __syncthreads();  // amax_l complete
  if (tid < 64) {
    sx[T0 + tid] = amax_l[tid] * (1.0f / 127.0f);
    tokid[T0 + tid] = ids_l[tid];
  }

  // ---- pass2: quantize the block's 64 rows (L3-hot), fully coalesced
  for (int row = 0; row < 64; ++row) {
    const float am = amax_l[row];
    const float inv = am > 0.f ? 127.0f / am : 0.f;
    const float* rp = x + (size_t)(T0 + row) * DIN + tid * 16;
    signed char* op = xq + (size_t)(T0 + row) * DIN + tid * 16;
    i32x4 pk;
#pragma unroll
    for (int i = 0; i < 4; ++i) {
      f32x4 v = *(const f32x4*)(rp + i * 4);
      pk[i] = ((int)rintf(v[0] * inv) & 255) | (((int)rintf(v[1] * inv) & 255) << 8) |
              (((int)rintf(v[2] * inv) & 255) << 16) | (((int)rintf(v[3] * inv) & 255) << 24);
    }
    *(i32x4*)op = pk;
  }
}

// ------------------------------------------------------------- main fused GEMM
// (unchanged from rounds 9/10 -- predictions matched twice: ~197us,
//  MfmaUtil 28.5, 0 bank conflicts)
// int8 NT-GEMM: iacc[t,o] = sum_k xq[t,k]*wq[o,k]; out = sx[t]*sw[o]*iacc
//             + bias[o] + LoRA (bf16 MFMA K=32 extension on the f32 acc).
__global__ __launch_bounds__(512, 2) void gemm_fused(const signed char* __restrict__ A_,
                                                     const signed char* __restrict__ B_,
                                                     const float* __restrict__ bias,
                                                     const float* __restrict__ hbuf,
                                                     const unsigned short* __restrict__ hb16,
                                                     const int* __restrict__ tokid,
                                                     const float* __restrict__ wbt,
                                                     const float* __restrict__ sxv,
                                                     const float* __restrict__ swv,
                                                     float* __restrict__ out) {
  __shared__ __align__(16) signed char As[2][BM * BK];  // 2 x 32 KB
  __shared__ __align__(16) signed char Bs[2][BN * BK];  // 2 x 32 KB
  __shared__ int s_nb;

  const int tid = threadIdx.x;
  const int lane = tid & 63;
  const int wave = tid >> 6;   // 0..7
  const int wr = wave >> 2;    // 0..1  M half
  const int wn = wave & 3;     // 0..3  N quarter

  // XCD-aware bijective swizzle: 512 blocks, 64-block chunk per XCD
  const int bsw = (blockIdx.x & 7) * 64 + (blockIdx.x >> 3);
  const int brow = (bsw >> 4) * BM;   // 32 M-blocks
  const int bcol = (bsw & 15) * BN;   // 16 N-blocks

  i32x4 acc[8][4] = {};

  const int g = lane >> 4;       // k-group 0..3
  const int rsel = lane & 15;    // fragment row select
  const int low3 = rsel & 7;     // swizzle phase (row & 7)

#define STAGE1(dst, bufp, h, tt, src, rb0)                                             \
  {                                                                                    \
    _Pragma("unroll")                                                                  \
    for (int i = 0; i < 2; ++i) {                                                      \
      const int lin2 = i * 512 + tid;                                                  \
      const int rr = lin2 >> 3;                                                        \
      const int klog = ((lin2 & 7) ^ (rr & 7)) * 16;  /* bytes */                      \
      const signed char* gp = (src) + (size_t)((rb0) + (h) * 128 + rr) * DIN + (tt) * BK + klog; \
      __builtin_amdgcn_global_load_lds(GLB_PTR(gp), LDS_PTR(&dst[bufp][(h) * 16384 + lin2 * 16]), 16, 0, 0); \
    }                                                                                  \
  }

#define RD_B(p)                                                                        \
  _Pragma("unroll") for (int kk = 0; kk < 2; ++kk)                                     \
  _Pragma("unroll") for (int n = 0; n < 4; ++n)                                        \
    bfr[n][kk] = *(const i32x4*)(&Bs[p][(wn * 64 + n * 16 + rsel) * BK + (((kk) * 4 + g) ^ low3) * 16]);

#define RD_A(AF, p, mo, kk)                                                            \
  _Pragma("unroll") for (int mi = 0; mi < 4; ++mi)                                     \
    AF[mi] = *(const i32x4*)(&As[p][(wr * 128 + ((mo) + mi) * 16 + rsel) * BK + (((kk) * 4 + g) ^ low3) * 16]);

#define MFMA16(mo, kk, AF)                                                             \
  _Pragma("unroll") for (int mi = 0; mi < 4; ++mi)                                     \
  _Pragma("unroll") for (int n = 0; n < 4; ++n)                                        \
    acc[(mo) + mi][n] = __builtin_amdgcn_mfma_i32_16x16x64_i8(AF[mi], bfr[n][kk],      \
                                                              acc[(mo) + mi][n], 0, 0, 0)

#define PH_OPEN()                                                                      \
  asm volatile("" ::: "memory");                                                       \
  __builtin_amdgcn_s_barrier();                                                        \
  asm volatile("s_waitcnt lgkmcnt(0)" ::: "memory");                                   \
  __builtin_amdgcn_sched_barrier(0);                                                   \
  __builtin_amdgcn_s_setprio(1)

#define PH_CLOSE()                                                                     \
  __builtin_amdgcn_s_setprio(0);                                                       \
  asm volatile("" ::: "memory");                                                       \
  __builtin_amdgcn_s_barrier();                                                        \
  asm volatile("" ::: "memory")

#define PH_CLOSE_VM(N)                                                                 \
  __builtin_amdgcn_s_setprio(0);                                                       \
  asm volatile("s_waitcnt vmcnt(" #N ")" ::: "memory");                                \
  __builtin_amdgcn_s_barrier();                                                        \
  asm volatile("" ::: "memory")

  // ---- prologue: A(0),B(0) -> buf0; B(1) -> buf1 (12 loads)
  STAGE1(As, 0, 0, 0, A_, brow);
  STAGE1(As, 0, 1, 0, A_, brow);
  STAGE1(Bs, 0, 0, 0, B_, bcol);
  STAGE1(Bs, 0, 1, 0, B_, bcol);
  STAGE1(Bs, 1, 0, 1, B_, bcol);
  STAGE1(Bs, 1, 1, 1, B_, bcol);
  asm volatile("s_waitcnt vmcnt(4)" ::: "memory");
  __builtin_amdgcn_s_barrier();
  asm volatile("" ::: "memory");

  for (int j = 0; j < NPAIR - 1; ++j) {
    const int v = 2 * j + 1;
    i32x4 bfr[4][2], afA[4], afB[4];
    RD_B(0); RD_A(afA, 0, 0, 0);
    STAGE1(As, 1, 0, v, A_, brow);
    PH_OPEN(); MFMA16(0, 0, afA); PH_CLOSE();
    RD_A(afB, 0, 4, 0);
    STAGE1(As, 1, 1, v, A_, brow);
    PH_OPEN(); MFMA16(4, 0, afB); PH_CLOSE();
    RD_A(afA, 0, 0, 1);
    STAGE1(Bs, 0, 0, v + 1, B_, bcol);
    PH_OPEN(); MFMA16(0, 1, afA); PH_CLOSE();
    RD_A(afB, 0, 4, 1);
    STAGE1(Bs, 0, 1, v + 1, B_, bcol);
    PH_OPEN(); MFMA16(4, 1, afB); PH_CLOSE_VM(4);
    RD_B(1); RD_A(afA, 1, 0, 0);
    STAGE1(As, 0, 0, v + 1, A_, brow);
    PH_OPEN(); MFMA16(0, 0, afA); PH_CLOSE();
    RD_A(afB, 1, 4, 0);
    STAGE1(As, 0, 1, v + 1, A_, brow);
    PH_OPEN(); MFMA16(4, 0, afB); PH_CLOSE();
    RD_A(afA, 1, 0, 1);
    STAGE1(Bs, 1, 0, v + 2, B_, bcol);
    PH_OPEN(); MFMA16(0, 1, afA); PH_CLOSE();
    RD_A(afB, 1, 4, 1);
    STAGE1(Bs, 1, 1, v + 2, B_, bcol);
    PH_OPEN(); MFMA16(4, 1, afB); PH_CLOSE_VM(4);
  }

  // ---- peeled final pair
  {
    const int v = NT - 1;
    i32x4 bfr[4][2], afA[4], afB[4];
    RD_B(0); RD_A(afA, 0, 0, 0);
    STAGE1(As, 1, 0, v, A_, brow);
    PH_OPEN(); MFMA16(0, 0, afA); PH_CLOSE();
    RD_A(afB, 0, 4, 0);
    STAGE1(As, 1, 1, v, A_, brow);
    PH_OPEN(); MFMA16(4, 0, afB); PH_CLOSE();
    RD_A(afA, 0, 0, 1);
    PH_OPEN(); MFMA16(0, 1, afA); PH_CLOSE();
    RD_A(afB, 0, 4, 1);
    PH_OPEN(); MFMA16(4, 1, afB); PH_CLOSE_VM(0);
    RD_B(1); RD_A(afA, 1, 0, 0);
    PH_OPEN(); MFMA16(0, 0, afA); PH_CLOSE();
    RD_A(afB, 1, 4, 0);
    PH_OPEN(); MFMA16(4, 0, afB); PH_CLOSE();
    RD_A(afA, 1, 0, 1);
    PH_OPEN(); MFMA16(0, 1, afA); PH_CLOSE();
    RD_A(afB, 1, 4, 1);
    PH_OPEN(); MFMA16(4, 1, afB); PH_CLOSE();
  }

  // ---- epilogue -------------------------------------------------------------
  const int rb = brow + wr * 128;
  const int cb = bcol + wn * 64;
  const int crow = g * 4;
  const int ccol = rsel;

  if (tid == 0) s_nb = 0;
  __syncthreads();
  if (tid >= 1 && tid < BM) {
    if (tokid[brow + tid] != tokid[brow + tid - 1]) atomicAdd(&s_nb, 1);
  }
  __syncthreads();
  const int nb = s_nb;
  const int idLo = tokid[brow];
  const int idHi = tokid[brow + BM - 1];

  float biasn[4], swn[4];
#pragma unroll
  for (int n = 0; n < 4; ++n) {
    biasn[n] = bias[cb + n * 16 + ccol];
    swn[n] = swv[cb + n * 16 + ccol];
  }

  f32x4 facc[8][4];
#pragma unroll
  for (int m = 0; m < 8; ++m) {
    float sxr[4];
#pragma unroll
    for (int jj = 0; jj < 4; ++jj) sxr[jj] = sxv[rb + m * 16 + crow + jj];
#pragma unroll
    for (int n = 0; n < 4; ++n)
#pragma unroll
      for (int jj = 0; jj < 4; ++jj)
        facc[m][n][jj] = (float)acc[m][n][jj] * (sxr[jj] * swn[n]);
  }

  if (nb <= 1) {
    const int myId = (g < 2) ? idLo : idHi;
    const int maskId = (g < 2) ? idLo : ((nb == 0) ? 0x80000000 : idHi);
    const float* wbase = wbt + (size_t)myId * RANK * DOUTF + (size_t)((g & 1) * 8) * DOUTF;
    bf16x8 bext[4];
#pragma unroll
    for (int n = 0; n < 4; ++n) {
      const int col = cb + n * 16 + ccol;
#pragma unroll
      for (int jj = 0; jj < 8; ++jj)
        bext[n][jj] = (short)f2bf(wbase[(size_t)jj * DOUTF + col]);
    }
#pragma unroll
    for (int m = 0; m < 8; ++m) {
      const int row = rb + m * 16 + rsel;
      const int rid = tokid[row];
      bf16x8 av = {};
      if (rid == maskId)
        av = *(const bf16x8*)(hb16 + (size_t)row * RANK + (g & 1) * 8);
#pragma unroll
      for (int n = 0; n < 4; ++n)
        facc[m][n] = __builtin_amdgcn_mfma_f32_16x16x32_bf16(av, bext[n], facc[m][n], 0, 0, 0);
    }
#pragma unroll
    for (int m = 0; m < 8; ++m) {
#pragma unroll
      for (int jj = 0; jj < 4; ++jj) {
        const int row = rb + m * 16 + crow + jj;
        float* orow = out + (size_t)row * DOUTF;
#pragma unroll
        for (int n = 0; n < 4; ++n)
          orow[cb + n * 16 + ccol] = facc[m][n][jj] + biasn[n];
      }
    }
  } else {
#pragma unroll
    for (int m = 0; m < 8; ++m) {
#pragma unroll
      for (int jj = 0; jj < 4; ++jj) {
        const int row = rb + m * 16 + crow + jj;
        const float4* hp = (const float4*)(hbuf + (size_t)row * RANK);
        float4 h0 = hp[0], h1 = hp[1], h2 = hp[2], h3 = hp[3];
        float hv[16] = {h0.x, h0.y, h0.z, h0.w, h1.x, h1.y, h1.z, h1.w,
                        h2.x, h2.y, h2.z, h2.w, h3.x, h3.y, h3.z, h3.w};
        const float* wrow = wbt + (size_t)tokid[row] * RANK * DOUTF;
        float* orow = out + (size_t)row * DOUTF;
#pragma unroll
        for (int n = 0; n < 4; ++n) {
          const int col = cb + n * 16 + ccol;
          float vsum = facc[m][n][jj] + biasn[n];
#pragma unroll
          for (int r = 0; r < 16; ++r) vsum += hv[r] * wrow[(size_t)r * DOUTF + col];
          orow[col] = vsum;
        }
      }
    }
  }
#undef STAGE1
#undef RD_A
#undef RD_B
#undef MFMA16
#undef PH_OPEN
#undef PH_CLOSE
#undef PH_CLOSE_VM
}

// ---------------------------------------------------------------------- launch
extern "C" void kernel_launch(void* const* d_in, const int* in_sizes, int n_in,
                              void* d_out, int out_size, void* d_ws, size_t ws_size,
                              hipStream_t stream) {
  const float* x       = (const float*)d_in[0];
  const float* base_w  = (const float*)d_in[1];
  const float* base_b  = (const float*)d_in[2];
  const float* wa      = (const float*)d_in[3];
  const float* wb      = (const float*)d_in[4];
  const float* scaling = (const float*)d_in[5];
  const int*   segment = (const int*)d_in[6];
  const int*   lora_id = (const int*)d_in[7];
  float* out = (float*)d_out;

  char* ws = (char*)d_ws;
  signed char* xq = (signed char*)ws;                                  // 32 MB
  signed char* wq = (signed char*)(ws + (size_t)T_TOK * DIN);          // 16 MB
  float* sx   = (float*)(ws + (size_t)T_TOK * DIN + (size_t)DOUTF * DIN);
  float* sw   = sx + T_TOK;
  float* hbuf = sw + DOUTF;
  int* tokid  = (int*)(hbuf + (size_t)T_TOK * RANK);
  unsigned short* hb16 = (unsigned short*)(tokid + T_TOK);

  prep<<<128 + DOUTF / 4, 256, 0, stream>>>(x, base_w, wa, scaling, segment, lora_id,
                                            xq, sx, wq, sw, hbuf, hb16, tokid);
  gemm_fused<<<(T_TOK / BM) * (DOUTF / BN), 512, 0, stream>>>(xq, wq, base_b, hbuf,
                                                              hb16, tokid, wb, sx, sw,
                                                              out);
}

// Round 12
// 291.077 us; speedup vs baseline: 1.1297x; 1.1297x over previous
//
#include <hip/hip_runtime.h>

#define T_TOK 8192
#define DIN   4096
#define DOUTF 4096
#define RANK  16

#define GBM 128
#define GBN 128
#define BK  128                // i8 elements per K-tile = 128 B rows
#define NT  (DIN / BK)         // 32 K-tiles

typedef __attribute__((ext_vector_type(4))) float f32x4;
typedef __attribute__((ext_vector_type(4))) int   i32x4;
typedef __attribute__((ext_vector_type(8))) short bf16x8;

#define GLB_PTR(p) ((const __attribute__((address_space(1))) void*)(p))
#define LDS_PTR(p) ((__attribute__((address_space(3))) void*)(p))

__device__ __forceinline__ unsigned short f2bf(float f) {
  unsigned u = __float_as_uint(f);
  u = (u + 0x7fffu + ((u >> 16) & 1u)) >> 16;  // RNE
  return (unsigned short)u;
}

// ---------------------------------------------------------------- fused prep
// (reverted to round-10's proven design -- r11's MFMA restructure was
//  latency-crippled by uncoalesced x gathers: prep 95 -> 211us)
// blocks [0,512): lora_h + x-quant (pass1 streams x f32 COALESCED, accumulates
//   LoRA acc and per-token absmax; pass2 re-reads the 4 rows L3-hot, writes i8).
// blocks [512,1536): per-row quant of base_w (reg-cached row, wave absmax).
__global__ __launch_bounds__(256) void prep(const float* __restrict__ x,
                                            const float* __restrict__ base_w,
                                            const float* __restrict__ wa,
                                            const float* __restrict__ scaling,
                                            const int* __restrict__ segment,
                                            const int* __restrict__ lora_ids,
                                            signed char* __restrict__ xq,
                                            float* __restrict__ sx,
                                            signed char* __restrict__ wq,
                                            float* __restrict__ sw,
                                            float* __restrict__ hbuf,
                                            unsigned short* __restrict__ hb16,
                                            int* __restrict__ tokid) {
  const int lane = threadIdx.x & 63;
  const int wave = threadIdx.x >> 6;

  if (blockIdx.x >= 512) {
    const int row = (blockIdx.x - 512) * 4 + wave;
    const float* rp = base_w + (size_t)row * DIN;
    f32x4 v[16];
    float amax = 0.f;
#pragma unroll
    for (int it = 0; it < 16; ++it) {
      v[it] = *(const f32x4*)(rp + it * 256 + lane * 4);
#pragma unroll
      for (int e = 0; e < 4; ++e) amax = fmaxf(amax, fabsf(v[it][e]));
    }
#pragma unroll
    for (int o = 1; o < 64; o <<= 1) amax = fmaxf(amax, __shfl_xor(amax, o));
    const float inv = amax > 0.f ? 127.0f / amax : 0.f;
    if (lane == 0) sw[row] = amax * (1.0f / 127.0f);
    signed char* op = wq + (size_t)row * DIN;
#pragma unroll
    for (int it = 0; it < 16; ++it) {
      const int q0 = (int)rintf(v[it][0] * inv);
      const int q1 = (int)rintf(v[it][1] * inv);
      const int q2 = (int)rintf(v[it][2] * inv);
      const int q3 = (int)rintf(v[it][3] * inv);
      *(int*)(op + it * 256 + lane * 4) =
          (q0 & 255) | ((q1 & 255) << 8) | ((q2 & 255) << 16) | ((q3 & 255) << 24);
    }
    return;
  }

  const int t0 = blockIdx.x * 16 + wave * 4;

  int ids[4]; float sc[4];
#pragma unroll
  for (int q = 0; q < 4; ++q) {
    int t = t0 + q;
    int s = 0;
#pragma unroll
    for (int i = 1; i < 8; ++i)
      if (t >= segment[i]) s = i;
    int id = lora_ids[s];
    ids[q] = id;
    sc[q] = scaling[id];
  }

  float acc[4][16];
  float amax[4] = {0.f, 0.f, 0.f, 0.f};
#pragma unroll
  for (int q = 0; q < 4; ++q)
#pragma unroll
    for (int r = 0; r < 16; ++r) acc[q][r] = 0.f;

  const bool same = (ids[0] == ids[1]) && (ids[1] == ids[2]) && (ids[2] == ids[3]);
  const int dbase = lane * 4;

  if (same) {
    const float* wrow = wa + (size_t)ids[0] * DIN * RANK;
#pragma unroll 2
    for (int it = 0; it < 16; ++it) {
      const int d = it * 256 + dbase;
      f32x4 xv[4];
#pragma unroll
      for (int q = 0; q < 4; ++q) {
        xv[q] = *(const f32x4*)(x + (size_t)(t0 + q) * DIN + d);
#pragma unroll
        for (int e = 0; e < 4; ++e) amax[q] = fmaxf(amax[q], fabsf(xv[q][e]));
      }
#pragma unroll
      for (int dd = 0; dd < 4; ++dd) {
        const f32x4* wp = (const f32x4*)(wrow + (size_t)(d + dd) * RANK);
        f32x4 w0 = wp[0], w1 = wp[1], w2 = wp[2], w3 = wp[3];
#pragma unroll
        for (int q = 0; q < 4; ++q) {
          const float xs = xv[q][dd];
#pragma unroll
          for (int r = 0; r < 4; ++r) {
            acc[q][r]      += xs * w0[r];
            acc[q][r + 4]  += xs * w1[r];
            acc[q][r + 8]  += xs * w2[r];
            acc[q][r + 12] += xs * w3[r];
          }
        }
      }
    }
  } else {
#pragma unroll
    for (int q = 0; q < 4; ++q) {
      const float* wrow = wa + (size_t)ids[q] * DIN * RANK;
      for (int it = 0; it < 16; ++it) {
        const int d = it * 256 + dbase;
        f32x4 xv = *(const f32x4*)(x + (size_t)(t0 + q) * DIN + d);
#pragma unroll
        for (int e = 0; e < 4; ++e) amax[q] = fmaxf(amax[q], fabsf(xv[e]));
#pragma unroll
        for (int dd = 0; dd < 4; ++dd) {
          const f32x4* wp = (const f32x4*)(wrow + (size_t)(d + dd) * RANK);
          f32x4 w0 = wp[0], w1 = wp[1], w2 = wp[2], w3 = wp[3];
          const float xs = xv[dd];
#pragma unroll
          for (int r = 0; r < 4; ++r) {
            acc[q][r]      += xs * w0[r];
            acc[q][r + 4]  += xs * w1[r];
            acc[q][r + 8]  += xs * w2[r];
            acc[q][r + 12] += xs * w3[r];
          }
        }
      }
    }
  }

#pragma unroll
  for (int q = 0; q < 4; ++q) {
#pragma unroll
    for (int r = 0; r < 16; ++r) {
      float v = acc[q][r];
      v += __shfl_xor(v, 1);
      v += __shfl_xor(v, 2);
      v += __shfl_xor(v, 4);
      v += __shfl_xor(v, 8);
      v += __shfl_xor(v, 16);
      v += __shfl_xor(v, 32);
      acc[q][r] = v;
    }
    if (lane == 0) {
      int t = t0 + q;
      tokid[t] = ids[q];
#pragma unroll
      for (int r = 0; r < 16; ++r) {
        float v = sc[q] * acc[q][r];
        hbuf[t * RANK + r] = v;
        hb16[t * RANK + r] = f2bf(v);
      }
    }
  }

  // quant pass: rows just streamed -> L2/L3-hot re-read
#pragma unroll
  for (int q = 0; q < 4; ++q) {
    float am = amax[q];
#pragma unroll
    for (int o = 1; o < 64; o <<= 1) am = fmaxf(am, __shfl_xor(am, o));
    const float inv = am > 0.f ? 127.0f / am : 0.f;
    if (lane == 0) sx[t0 + q] = am * (1.0f / 127.0f);
    const float* rp = x + (size_t)(t0 + q) * DIN;
    signed char* op = xq + (size_t)(t0 + q) * DIN;
#pragma unroll 4
    for (int it = 0; it < 16; ++it) {
      f32x4 v = *(const f32x4*)(rp + it * 256 + dbase);
      const int q0 = (int)rintf(v[0] * inv);
      const int q1 = (int)rintf(v[1] * inv);
      const int q2 = (int)rintf(v[2] * inv);
      const int q3 = (int)rintf(v[3] * inv);
      *(int*)(op + it * 256 + dbase) =
          (q0 & 255) | ((q1 & 255) << 8) | ((q2 & 255) << 16) | ((q3 & 255) << 24);
    }
  }
}

// ------------------------------------------------------------- main fused GEMM
// r12: 128x128 tile, BK=128 i8, 4 waves (2x2, per-wave 64x64), 2-deep double
// buffer = 64 KB LDS -> 2 BLOCKS/CU (8 waves/CU, __launch_bounds__(256,2) ->
// 256-VGPR cap, acc only 64 regs so NO spill -- r7's TLP mechanism at a
// register-feasible geometry). When one block sits in its barrier convoy the
// co-resident block's MFMA/LDS work fills the SIMDs (m114). Per tile:
// {16 ds_reads -> setprio 32 MFMA -> barrier -> STAGE(t+2) -> vmcnt(8)
// (t+1 landed, t+2's 8 in flight, never 0) -> barrier}. XOR swizzle
// (phys chunk = logical ^ (row&7)) on staging source and ds_read (proven 0
// conflicts r2-r11). Epilogue: separable scales + bf16 MFMA LoRA extension.
__global__ __launch_bounds__(256, 2) void gemm_fused(const signed char* __restrict__ A_,
                                                     const signed char* __restrict__ B_,
                                                     const float* __restrict__ bias,
                                                     const float* __restrict__ hbuf,
                                                     const unsigned short* __restrict__ hb16,
                                                     const int* __restrict__ tokid,
                                                     const float* __restrict__ wbt,
                                                     const float* __restrict__ sxv,
                                                     const float* __restrict__ swv,
                                                     float* __restrict__ out) {
  __shared__ __align__(16) signed char As[2][GBM * BK];  // 2 x 16 KB
  __shared__ __align__(16) signed char Bs[2][GBN * BK];  // 2 x 16 KB
  __shared__ int s_nb;

  const int tid = threadIdx.x;
  const int lane = tid & 63;
  const int wave = tid >> 6;   // 0..3
  const int wr = wave >> 1;    // 0..1  M half
  const int wc = wave & 1;     // 0..1  N half

  // XCD-aware bijective swizzle: 2048 blocks, 256-block chunk per XCD
  const int bsw = (blockIdx.x & 7) * 256 + (blockIdx.x >> 3);
  const int brow = (bsw >> 5) * GBM;   // 64 M-blocks
  const int bcol = (bsw & 31) * GBN;   // 32 N-blocks

  i32x4 acc[4][4] = {};

  const int g = lane >> 4;       // k-group 0..3
  const int rsel = lane & 15;    // fragment row select
  const int low3 = rsel & 7;     // swizzle phase (row & 7)

#define STAGE(p, tt)                                                                   \
  {                                                                                    \
    _Pragma("unroll")                                                                  \
    for (int i = 0; i < 4; ++i) {                                                      \
      const int lin = i * 256 + tid;       /* 0..1023 */                               \
      const int rr = lin >> 3;             /* row 0..127 */                            \
      const int klog = ((lin & 7) ^ (rr & 7)) * 16;  /* bytes */                       \
      const signed char* gA = A_ + (size_t)(brow + rr) * DIN + (tt) * BK + klog;       \
      const signed char* gB = B_ + (size_t)(bcol + rr) * DIN + (tt) * BK + klog;       \
      __builtin_amdgcn_global_load_lds(GLB_PTR(gA), LDS_PTR(&As[p][lin * 16]), 16, 0, 0); \
      __builtin_amdgcn_global_load_lds(GLB_PTR(gB), LDS_PTR(&Bs[p][lin * 16]), 16, 0, 0); \
    }                                                                                  \
  }

  STAGE(0, 0);
  STAGE(1, 1);
  asm volatile("s_waitcnt vmcnt(8)" ::: "memory");  // tile 0 landed; tile 1 in flight
  __builtin_amdgcn_s_barrier();
  asm volatile("" ::: "memory");

  for (int t = 0; t < NT; ++t) {
    const int p = t & 1;

    i32x4 bfr[2][4], afr[2][4];
#pragma unroll
    for (int kk = 0; kk < 2; ++kk) {
      const int ph = ((kk * 4 + g) ^ low3) * 16;
#pragma unroll
      for (int n = 0; n < 4; ++n)
        bfr[kk][n] = *(const i32x4*)(&Bs[p][(wc * 64 + n * 16 + rsel) * BK + ph]);
#pragma unroll
      for (int m = 0; m < 4; ++m)
        afr[kk][m] = *(const i32x4*)(&As[p][(wr * 64 + m * 16 + rsel) * BK + ph]);
    }

    __builtin_amdgcn_s_setprio(1);
#pragma unroll
    for (int kk = 0; kk < 2; ++kk)
#pragma unroll
      for (int m = 0; m < 4; ++m)
#pragma unroll
        for (int n = 0; n < 4; ++n)
          acc[m][n] = __builtin_amdgcn_mfma_i32_16x16x64_i8(afr[kk][m], bfr[kk][n],
                                                            acc[m][n], 0, 0, 0);
    __builtin_amdgcn_s_setprio(0);

    // barrier1: all waves' reads of buf p are complete
    asm volatile("" ::: "memory");
    __builtin_amdgcn_s_barrier();
    asm volatile("" ::: "memory");

    if (t + 2 < NT) {
      STAGE(p, t + 2);
      asm volatile("s_waitcnt vmcnt(8)" ::: "memory");  // t+1 landed; t+2 in flight
    } else if (t + 1 < NT) {
      asm volatile("s_waitcnt vmcnt(0)" ::: "memory");
    }
    __builtin_amdgcn_s_barrier();
    asm volatile("" ::: "memory");
  }

  // ---- epilogue -------------------------------------------------------------
  const int rb = brow + wr * 64;
  const int cb = bcol + wc * 64;
  const int crow = g * 4;        // C/D row = (lane>>4)*4 + jj (dtype-independent)
  const int ccol = rsel;

  if (tid == 0) s_nb = 0;
  __syncthreads();
  if (tid >= 1 && tid < GBM) {
    if (tokid[brow + tid] != tokid[brow + tid - 1]) atomicAdd(&s_nb, 1);
  }
  __syncthreads();
  const int nb = s_nb;
  const int idLo = tokid[brow];
  const int idHi = tokid[brow + GBM - 1];

  float biasn[4], swn[4];
#pragma unroll
  for (int n = 0; n < 4; ++n) {
    biasn[n] = bias[cb + n * 16 + ccol];
    swn[n] = swv[cb + n * 16 + ccol];
  }

  f32x4 facc[4][4];
#pragma unroll
  for (int m = 0; m < 4; ++m) {
    float sxr[4];
#pragma unroll
    for (int jj = 0; jj < 4; ++jj) sxr[jj] = sxv[rb + m * 16 + crow + jj];
#pragma unroll
    for (int n = 0; n < 4; ++n)
#pragma unroll
      for (int jj = 0; jj < 4; ++jj)
        facc[m][n][jj] = (float)acc[m][n][jj] * (sxr[jj] * swn[n]);
  }

  if (nb <= 1) {
    // MFMA K=32 extension: k<16 -> adapter idLo, k>=16 -> adapter idHi
    const int myId = (g < 2) ? idLo : idHi;
    const int maskId = (g < 2) ? idLo : ((nb == 0) ? 0x80000000 : idHi);
    const float* wbase = wbt + (size_t)myId * RANK * DOUTF + (size_t)((g & 1) * 8) * DOUTF;
    bf16x8 bext[4];
#pragma unroll
    for (int n = 0; n < 4; ++n) {
      const int col = cb + n * 16 + ccol;
#pragma unroll
      for (int jj = 0; jj < 8; ++jj)
        bext[n][jj] = (short)f2bf(wbase[(size_t)jj * DOUTF + col]);
    }
#pragma unroll
    for (int m = 0; m < 4; ++m) {
      const int row = rb + m * 16 + rsel;
      const int rid = tokid[row];
      bf16x8 av = {};
      if (rid == maskId)
        av = *(const bf16x8*)(hb16 + (size_t)row * RANK + (g & 1) * 8);
#pragma unroll
      for (int n = 0; n < 4; ++n)
        facc[m][n] = __builtin_amdgcn_mfma_f32_16x16x32_bf16(av, bext[n], facc[m][n], 0, 0, 0);
    }
#pragma unroll
    for (int m = 0; m < 4; ++m) {
#pragma unroll
      for (int jj = 0; jj < 4; ++jj) {
        const int row = rb + m * 16 + crow + jj;
        float* orow = out + (size_t)row * DOUTF;
#pragma unroll
        for (int n = 0; n < 4; ++n)
          orow[cb + n * 16 + ccol] = facc[m][n][jj] + biasn[n];
      }
    }
  } else {
    // rare fallback: per-row scalar LoRA
#pragma unroll
    for (int m = 0; m < 4; ++m) {
#pragma unroll
      for (int jj = 0; jj < 4; ++jj) {
        const int row = rb + m * 16 + crow + jj;
        const float4* hp = (const float4*)(hbuf + (size_t)row * RANK);
        float4 h0 = hp[0], h1 = hp[1], h2 = hp[2], h3 = hp[3];
        float hv[16] = {h0.x, h0.y, h0.z, h0.w, h1.x, h1.y, h1.z, h1.w,
                        h2.x, h2.y, h2.z, h2.w, h3.x, h3.y, h3.z, h3.w};
        const float* wrow = wbt + (size_t)tokid[row] * RANK * DOUTF;
        float* orow = out + (size_t)row * DOUTF;
#pragma unroll
        for (int n = 0; n < 4; ++n) {
          const int col = cb + n * 16 + ccol;
          float vsum = facc[m][n][jj] + biasn[n];
#pragma unroll
          for (int r = 0; r < 16; ++r) vsum += hv[r] * wrow[(size_t)r * DOUTF + col];
          orow[col] = vsum;
        }
      }
    }
  }
#undef STAGE
}

// ---------------------------------------------------------------------- launch
extern "C" void kernel_launch(void* const* d_in, const int* in_sizes, int n_in,
                              void* d_out, int out_size, void* d_ws, size_t ws_size,
                              hipStream_t stream) {
  const float* x       = (const float*)d_in[0];
  const float* base_w  = (const float*)d_in[1];
  const float* base_b  = (const float*)d_in[2];
  const float* wa      = (const float*)d_in[3];
  const float* wb      = (const float*)d_in[4];
  const float* scaling = (const float*)d_in[5];
  const int*   segment = (const int*)d_in[6];
  const int*   lora_id = (const int*)d_in[7];
  float* out = (float*)d_out;

  char* ws = (char*)d_ws;
  signed char* xq = (signed char*)ws;                                  // 32 MB
  signed char* wq = (signed char*)(ws + (size_t)T_TOK * DIN);          // 16 MB
  float* sx   = (float*)(ws + (size_t)T_TOK * DIN + (size_t)DOUTF * DIN);
  float* sw   = sx + T_TOK;
  float* hbuf = sw + DOUTF;
  int* tokid  = (int*)(hbuf + (size_t)T_TOK * RANK);
  unsigned short* hb16 = (unsigned short*)(tokid + T_TOK);

  prep<<<512 + DOUTF / 4, 256, 0, stream>>>(x, base_w, wa, scaling, segment, lora_id,
                                            xq, sx, wq, sw, hbuf, hb16, tokid);
  gemm_fused<<<(T_TOK / GBM) * (DOUTF / GBN), 256, 0, stream>>>(xq, wq, base_b, hbuf,
                                                                hb16, tokid, wb, sx, sw,
                                                                out);
}

// Round 13
// 281.804 us; speedup vs baseline: 1.1668x; 1.0329x over previous
//
#include <hip/hip_runtime.h>

#define T_TOK 8192
#define DIN   4096
#define DOUTF 4096
#define RANK  16

#define BM 256
#define BN 256
#define BK 128                 // i8 elements per K-tile = 128 B rows
#define NT (DIN / BK)          // 32 K-tiles
#define NPAIR (NT / 2)         // 16 iterations, 2 K-tiles each

typedef __attribute__((ext_vector_type(4))) float f32x4;
typedef __attribute__((ext_vector_type(4))) int   i32x4;
typedef __attribute__((ext_vector_type(8))) short bf16x8;

#define GLB_PTR(p) ((const __attribute__((address_space(1))) void*)(p))
#define LDS_PTR(p) ((__attribute__((address_space(3))) void*)(p))

__device__ __forceinline__ unsigned short f2bf(float f) {
  unsigned u = __float_as_uint(f);
  u = (u + 0x7fffu + ((u >> 16) & 1u)) >> 16;  // RNE
  return (unsigned short)u;
}

// ---------------------------------------------------------------- fused prep
// (r10's proven design; r12 confirmed ~70us total non-GEMM)
__global__ __launch_bounds__(256) void prep(const float* __restrict__ x,
                                            const float* __restrict__ base_w,
                                            const float* __restrict__ wa,
                                            const float* __restrict__ scaling,
                                            const int* __restrict__ segment,
                                            const int* __restrict__ lora_ids,
                                            signed char* __restrict__ xq,
                                            float* __restrict__ sx,
                                            signed char* __restrict__ wq,
                                            float* __restrict__ sw,
                                            float* __restrict__ hbuf,
                                            unsigned short* __restrict__ hb16,
                                            int* __restrict__ tokid) {
  const int lane = threadIdx.x & 63;
  const int wave = threadIdx.x >> 6;

  if (blockIdx.x >= 512) {
    const int row = (blockIdx.x - 512) * 4 + wave;
    const float* rp = base_w + (size_t)row * DIN;
    f32x4 v[16];
    float amax = 0.f;
#pragma unroll
    for (int it = 0; it < 16; ++it) {
      v[it] = *(const f32x4*)(rp + it * 256 + lane * 4);
#pragma unroll
      for (int e = 0; e < 4; ++e) amax = fmaxf(amax, fabsf(v[it][e]));
    }
#pragma unroll
    for (int o = 1; o < 64; o <<= 1) amax = fmaxf(amax, __shfl_xor(amax, o));
    const float inv = amax > 0.f ? 127.0f / amax : 0.f;
    if (lane == 0) sw[row] = amax * (1.0f / 127.0f);
    signed char* op = wq + (size_t)row * DIN;
#pragma unroll
    for (int it = 0; it < 16; ++it) {
      const int q0 = (int)rintf(v[it][0] * inv);
      const int q1 = (int)rintf(v[it][1] * inv);
      const int q2 = (int)rintf(v[it][2] * inv);
      const int q3 = (int)rintf(v[it][3] * inv);
      *(int*)(op + it * 256 + lane * 4) =
          (q0 & 255) | ((q1 & 255) << 8) | ((q2 & 255) << 16) | ((q3 & 255) << 24);
    }
    return;
  }

  const int t0 = blockIdx.x * 16 + wave * 4;

  int ids[4]; float sc[4];
#pragma unroll
  for (int q = 0; q < 4; ++q) {
    int t = t0 + q;
    int s = 0;
#pragma unroll
    for (int i = 1; i < 8; ++i)
      if (t >= segment[i]) s = i;
    int id = lora_ids[s];
    ids[q] = id;
    sc[q] = scaling[id];
  }

  float acc[4][16];
  float amax[4] = {0.f, 0.f, 0.f, 0.f};
#pragma unroll
  for (int q = 0; q < 4; ++q)
#pragma unroll
    for (int r = 0; r < 16; ++r) acc[q][r] = 0.f;

  const bool same = (ids[0] == ids[1]) && (ids[1] == ids[2]) && (ids[2] == ids[3]);
  const int dbase = lane * 4;

  if (same) {
    const float* wrow = wa + (size_t)ids[0] * DIN * RANK;
#pragma unroll 2
    for (int it = 0; it < 16; ++it) {
      const int d = it * 256 + dbase;
      f32x4 xv[4];
#pragma unroll
      for (int q = 0; q < 4; ++q) {
        xv[q] = *(const f32x4*)(x + (size_t)(t0 + q) * DIN + d);
#pragma unroll
        for (int e = 0; e < 4; ++e) amax[q] = fmaxf(amax[q], fabsf(xv[q][e]));
      }
#pragma unroll
      for (int dd = 0; dd < 4; ++dd) {
        const f32x4* wp = (const f32x4*)(wrow + (size_t)(d + dd) * RANK);
        f32x4 w0 = wp[0], w1 = wp[1], w2 = wp[2], w3 = wp[3];
#pragma unroll
        for (int q = 0; q < 4; ++q) {
          const float xs = xv[q][dd];
#pragma unroll
          for (int r = 0; r < 4; ++r) {
            acc[q][r]      += xs * w0[r];
            acc[q][r + 4]  += xs * w1[r];
            acc[q][r + 8]  += xs * w2[r];
            acc[q][r + 12] += xs * w3[r];
          }
        }
      }
    }
  } else {
#pragma unroll
    for (int q = 0; q < 4; ++q) {
      const float* wrow = wa + (size_t)ids[q] * DIN * RANK;
      for (int it = 0; it < 16; ++it) {
        const int d = it * 256 + dbase;
        f32x4 xv = *(const f32x4*)(x + (size_t)(t0 + q) * DIN + d);
#pragma unroll
        for (int e = 0; e < 4; ++e) amax[q] = fmaxf(amax[q], fabsf(xv[e]));
#pragma unroll
        for (int dd = 0; dd < 4; ++dd) {
          const f32x4* wp = (const f32x4*)(wrow + (size_t)(d + dd) * RANK);
          f32x4 w0 = wp[0], w1 = wp[1], w2 = wp[2], w3 = wp[3];
          const float xs = xv[dd];
#pragma unroll
          for (int r = 0; r < 4; ++r) {
            acc[q][r]      += xs * w0[r];
            acc[q][r + 4]  += xs * w1[r];
            acc[q][r + 8]  += xs * w2[r];
            acc[q][r + 12] += xs * w3[r];
          }
        }
      }
    }
  }

#pragma unroll
  for (int q = 0; q < 4; ++q) {
#pragma unroll
    for (int r = 0; r < 16; ++r) {
      float v = acc[q][r];
      v += __shfl_xor(v, 1);
      v += __shfl_xor(v, 2);
      v += __shfl_xor(v, 4);
      v += __shfl_xor(v, 8);
      v += __shfl_xor(v, 16);
      v += __shfl_xor(v, 32);
      acc[q][r] = v;
    }
    if (lane == 0) {
      int t = t0 + q;
      tokid[t] = ids[q];
#pragma unroll
      for (int r = 0; r < 16; ++r) {
        float v = sc[q] * acc[q][r];
        hbuf[t * RANK + r] = v;
        hb16[t * RANK + r] = f2bf(v);
      }
    }
  }

#pragma unroll
  for (int q = 0; q < 4; ++q) {
    float am = amax[q];
#pragma unroll
    for (int o = 1; o < 64; o <<= 1) am = fmaxf(am, __shfl_xor(am, o));
    const float inv = am > 0.f ? 127.0f / am : 0.f;
    if (lane == 0) sx[t0 + q] = am * (1.0f / 127.0f);
    const float* rp = x + (size_t)(t0 + q) * DIN;
    signed char* op = xq + (size_t)(t0 + q) * DIN;
#pragma unroll 4
    for (int it = 0; it < 16; ++it) {
      f32x4 v = *(const f32x4*)(rp + it * 256 + dbase);
      const int q0 = (int)rintf(v[0] * inv);
      const int q1 = (int)rintf(v[1] * inv);
      const int q2 = (int)rintf(v[2] * inv);
      const int q3 = (int)rintf(v[3] * inv);
      *(int*)(op + it * 256 + dbase) =
          (q0 & 255) | ((q1 & 255) << 8) | ((q2 & 255) << 16) | ((q3 & 255) << 24);
    }
  }
}

// ------------------------------------------------------------- main fused GEMM
// r13: r9's proven 256x256 i8 BK=128 structure (197.5us) with phases MERGED
// 4->2 per K-tile: each phase now reads one full kk-slice (8 A-quads; B once
// per K-tile) and runs a 32-MFMA cluster. Barriers per pair-iteration 16->8.
// Stage slots: ph0 A(v)->buf1(full), ph1 B(u+2)->buf0 + vmcnt(4),
// ph2 A(u+2)->buf0, ph3 B(v+2)->buf1 + vmcnt(4). Audited: in-flight insts
// 4->8->12-wait(4)->8->12-wait(4)->4; every staged region's readers lgkm-drain
// >=1 barrier before overwrite; vmcnt never 0 in the main loop. Register-
// neutral vs r9 (AF[8]=32 regs replaces afA[4]+afB[4]). XOR swizzle unchanged.
__global__ __launch_bounds__(512, 2) void gemm_fused(const signed char* __restrict__ A_,
                                                     const signed char* __restrict__ B_,
                                                     const float* __restrict__ bias,
                                                     const float* __restrict__ hbuf,
                                                     const unsigned short* __restrict__ hb16,
                                                     const int* __restrict__ tokid,
                                                     const float* __restrict__ wbt,
                                                     const float* __restrict__ sxv,
                                                     const float* __restrict__ swv,
                                                     float* __restrict__ out) {
  __shared__ __align__(16) signed char As[2][BM * BK];  // 2 x 32 KB
  __shared__ __align__(16) signed char Bs[2][BN * BK];  // 2 x 32 KB
  __shared__ int s_nb;

  const int tid = threadIdx.x;
  const int lane = tid & 63;
  const int wave = tid >> 6;   // 0..7
  const int wr = wave >> 2;    // 0..1  M half
  const int wn = wave & 3;     // 0..3  N quarter

  const int bsw = (blockIdx.x & 7) * 64 + (blockIdx.x >> 3);
  const int brow = (bsw >> 4) * BM;
  const int bcol = (bsw & 15) * BN;

  i32x4 acc[8][4] = {};

  const int g = lane >> 4;
  const int rsel = lane & 15;
  const int low3 = rsel & 7;

#define STAGE1(dst, bufp, h, tt, src, rb0)                                             \
  {                                                                                    \
    _Pragma("unroll")                                                                  \
    for (int i = 0; i < 2; ++i) {                                                      \
      const int lin2 = i * 512 + tid;                                                  \
      const int rr = lin2 >> 3;                                                        \
      const int klog = ((lin2 & 7) ^ (rr & 7)) * 16;                                   \
      const signed char* gp = (src) + (size_t)((rb0) + (h) * 128 + rr) * DIN + (tt) * BK + klog; \
      __builtin_amdgcn_global_load_lds(GLB_PTR(gp), LDS_PTR(&dst[bufp][(h) * 16384 + lin2 * 16]), 16, 0, 0); \
    }                                                                                  \
  }

#define RD_B(p)                                                                        \
  _Pragma("unroll") for (int kk = 0; kk < 2; ++kk)                                     \
  _Pragma("unroll") for (int n = 0; n < 4; ++n)                                        \
    bfr[n][kk] = *(const i32x4*)(&Bs[p][(wn * 64 + n * 16 + rsel) * BK + (((kk) * 4 + g) ^ low3) * 16]);

#define RD_A8(AF, p, kk)                                                               \
  _Pragma("unroll") for (int mi = 0; mi < 8; ++mi)                                     \
    AF[mi] = *(const i32x4*)(&As[p][(wr * 128 + mi * 16 + rsel) * BK + (((kk) * 4 + g) ^ low3) * 16]);

#define MFMA32(kk, AF)                                                                 \
  _Pragma("unroll") for (int mi = 0; mi < 8; ++mi)                                     \
  _Pragma("unroll") for (int n = 0; n < 4; ++n)                                        \
    acc[mi][n] = __builtin_amdgcn_mfma_i32_16x16x64_i8(AF[mi], bfr[n][kk],             \
                                                       acc[mi][n], 0, 0, 0)

#define PH_OPEN()                                                                      \
  asm volatile("" ::: "memory");                                                       \
  __builtin_amdgcn_s_barrier();                                                        \
  asm volatile("s_waitcnt lgkmcnt(0)" ::: "memory");                                   \
  __builtin_amdgcn_sched_barrier(0);                                                   \
  __builtin_amdgcn_s_setprio(1)

#define PH_CLOSE()                                                                     \
  __builtin_amdgcn_s_setprio(0);                                                       \
  asm volatile("" ::: "memory");                                                       \
  __builtin_amdgcn_s_barrier();                                                        \
  asm volatile("" ::: "memory")

#define PH_CLOSE_VM(N)                                                                 \
  __builtin_amdgcn_s_setprio(0);                                                       \
  asm volatile("s_waitcnt vmcnt(" #N ")" ::: "memory");                                \
  __builtin_amdgcn_s_barrier();                                                        \
  asm volatile("" ::: "memory")

  // ---- prologue: A(0),B(0) -> buf0; B(1) -> buf1 (12 load insts)
  STAGE1(As, 0, 0, 0, A_, brow);
  STAGE1(As, 0, 1, 0, A_, brow);
  STAGE1(Bs, 0, 0, 0, B_, bcol);
  STAGE1(Bs, 0, 1, 0, B_, bcol);
  STAGE1(Bs, 1, 0, 1, B_, bcol);
  STAGE1(Bs, 1, 1, 1, B_, bcol);
  asm volatile("s_waitcnt vmcnt(4)" ::: "memory");  // tile0 landed; B(1) in flight
  __builtin_amdgcn_s_barrier();
  asm volatile("" ::: "memory");

  for (int j = 0; j < NPAIR - 1; ++j) {
    const int u = 2 * j, v = u + 1;
    i32x4 bfr[4][2], AF[8];
    // ph0: buf0 kk0 (16 ds_reads); stage A(v) full -> buf1
    RD_B(0); RD_A8(AF, 0, 0);
    STAGE1(As, 1, 0, v, A_, brow);
    STAGE1(As, 1, 1, v, A_, brow);
    PH_OPEN(); MFMA32(0, AF); PH_CLOSE();
    // ph1: buf0 kk1; stage B(u+2) -> buf0; wait: B(v),A(v) landed
    RD_A8(AF, 0, 1);
    STAGE1(Bs, 0, 0, u + 2, B_, bcol);
    STAGE1(Bs, 0, 1, u + 2, B_, bcol);
    PH_OPEN(); MFMA32(1, AF); PH_CLOSE_VM(4);
    // ph2: buf1 kk0; stage A(u+2) -> buf0
    RD_B(1); RD_A8(AF, 1, 0);
    STAGE1(As, 0, 0, u + 2, A_, brow);
    STAGE1(As, 0, 1, u + 2, A_, brow);
    PH_OPEN(); MFMA32(0, AF); PH_CLOSE();
    // ph3: buf1 kk1; stage B(v+2) -> buf1; wait: B(u+2),A(u+2) landed
    RD_A8(AF, 1, 1);
    STAGE1(Bs, 1, 0, v + 2, B_, bcol);
    STAGE1(Bs, 1, 1, v + 2, B_, bcol);
    PH_OPEN(); MFMA32(1, AF); PH_CLOSE_VM(4);
  }

  // ---- peeled final pair (u=NT-2, v=NT-1)
  {
    const int v = NT - 1;
    i32x4 bfr[4][2], AF[8];
    RD_B(0); RD_A8(AF, 0, 0);
    STAGE1(As, 1, 0, v, A_, brow);
    STAGE1(As, 1, 1, v, A_, brow);
    PH_OPEN(); MFMA32(0, AF); PH_CLOSE();
    RD_A8(AF, 0, 1);
    PH_OPEN(); MFMA32(1, AF); PH_CLOSE_VM(0);
    RD_B(1); RD_A8(AF, 1, 0);
    PH_OPEN(); MFMA32(0, AF); PH_CLOSE();
    RD_A8(AF, 1, 1);
    PH_OPEN(); MFMA32(1, AF); PH_CLOSE();
  }

  // ---- epilogue (unchanged from r9) ----------------------------------------
  const int rb = brow + wr * 128;
  const int cb = bcol + wn * 64;
  const int crow = g * 4;
  const int ccol = rsel;

  if (tid == 0) s_nb = 0;
  __syncthreads();
  if (tid >= 1 && tid < BM) {
    if (tokid[brow + tid] != tokid[brow + tid - 1]) atomicAdd(&s_nb, 1);
  }
  __syncthreads();
  const int nb = s_nb;
  const int idLo = tokid[brow];
  const int idHi = tokid[brow + BM - 1];

  float biasn[4], swn[4];
#pragma unroll
  for (int n = 0; n < 4; ++n) {
    biasn[n] = bias[cb + n * 16 + ccol];
    swn[n] = swv[cb + n * 16 + ccol];
  }

  f32x4 facc[8][4];
#pragma unroll
  for (int m = 0; m < 8; ++m) {
    float sxr[4];
#pragma unroll
    for (int jj = 0; jj < 4; ++jj) sxr[jj] = sxv[rb + m * 16 + crow + jj];
#pragma unroll
    for (int n = 0; n < 4; ++n)
#pragma unroll
      for (int jj = 0; jj < 4; ++jj)
        facc[m][n][jj] = (float)acc[m][n][jj] * (sxr[jj] * swn[n]);
  }

  if (nb <= 1) {
    const int myId = (g < 2) ? idLo : idHi;
    const int maskId = (g < 2) ? idLo : ((nb == 0) ? 0x80000000 : idHi);
    const float* wbase = wbt + (size_t)myId * RANK * DOUTF + (size_t)((g & 1) * 8) * DOUTF;
    bf16x8 bext[4];
#pragma unroll
    for (int n = 0; n < 4; ++n) {
      const int col = cb + n * 16 + ccol;
#pragma unroll
      for (int jj = 0; jj < 8; ++jj)
        bext[n][jj] = (short)f2bf(wbase[(size_t)jj * DOUTF + col]);
    }
#pragma unroll
    for (int m = 0; m < 8; ++m) {
      const int row = rb + m * 16 + rsel;
      const int rid = tokid[row];
      bf16x8 av = {};
      if (rid == maskId)
        av = *(const bf16x8*)(hb16 + (size_t)row * RANK + (g & 1) * 8);
#pragma unroll
      for (int n = 0; n < 4; ++n)
        facc[m][n] = __builtin_amdgcn_mfma_f32_16x16x32_bf16(av, bext[n], facc[m][n], 0, 0, 0);
    }
#pragma unroll
    for (int m = 0; m < 8; ++m) {
#pragma unroll
      for (int jj = 0; jj < 4; ++jj) {
        const int row = rb + m * 16 + crow + jj;
        float* orow = out + (size_t)row * DOUTF;
#pragma unroll
        for (int n = 0; n < 4; ++n)
          orow[cb + n * 16 + ccol] = facc[m][n][jj] + biasn[n];
      }
    }
  } else {
#pragma unroll
    for (int m = 0; m < 8; ++m) {
#pragma unroll
      for (int jj = 0; jj < 4; ++jj) {
        const int row = rb + m * 16 + crow + jj;
        const float4* hp = (const float4*)(hbuf + (size_t)row * RANK);
        float4 h0 = hp[0], h1 = hp[1], h2 = hp[2], h3 = hp[3];
        float hv[16] = {h0.x, h0.y, h0.z, h0.w, h1.x, h1.y, h1.z, h1.w,
                        h2.x, h2.y, h2.z, h2.w, h3.x, h3.y, h3.z, h3.w};
        const float* wrow = wbt + (size_t)tokid[row] * RANK * DOUTF;
        float* orow = out + (size_t)row * DOUTF;
#pragma unroll
        for (int n = 0; n < 4; ++n) {
          const int col = cb + n * 16 + ccol;
          float vsum = facc[m][n][jj] + biasn[n];
#pragma unroll
          for (int r = 0; r < 16; ++r) vsum += hv[r] * wrow[(size_t)r * DOUTF + col];
          orow[col] = vsum;
        }
      }
    }
  }
#undef STAGE1
#undef RD_A8
#undef RD_B
#undef MFMA32
#undef PH_OPEN
#undef PH_CLOSE
#undef PH_CLOSE_VM
}

// ---------------------------------------------------------------------- launch
extern "C" void kernel_launch(void* const* d_in, const int* in_sizes, int n_in,
                              void* d_out, int out_size, void* d_ws, size_t ws_size,
                              hipStream_t stream) {
  const float* x       = (const float*)d_in[0];
  const float* base_w  = (const float*)d_in[1];
  const float* base_b  = (const float*)d_in[2];
  const float* wa      = (const float*)d_in[3];
  const float* wb      = (const float*)d_in[4];
  const float* scaling = (const float*)d_in[5];
  const int*   segment = (const int*)d_in[6];
  const int*   lora_id = (const int*)d_in[7];
  float* out = (float*)d_out;

  char* ws = (char*)d_ws;
  signed char* xq = (signed char*)ws;                                  // 32 MB
  signed char* wq = (signed char*)(ws + (size_t)T_TOK * DIN);          // 16 MB
  float* sx   = (float*)(ws + (size_t)T_TOK * DIN + (size_t)DOUTF * DIN);
  float* sw   = sx + T_TOK;
  float* hbuf = sw + DOUTF;
  int* tokid  = (int*)(hbuf + (size_t)T_TOK * RANK);
  unsigned short* hb16 = (unsigned short*)(tokid + T_TOK);

  prep<<<512 + DOUTF / 4, 256, 0, stream>>>(x, base_w, wa, scaling, segment, lora_id,
                                            xq, sx, wq, sw, hbuf, hb16, tokid);
  gemm_fused<<<(T_TOK / BM) * (DOUTF / BN), 512, 0, stream>>>(xq, wq, base_b, hbuf,
                                                              hb16, tokid, wb, sx, sw,
                                                              out);
}